// Round 3
// baseline (491.858 us; speedup 1.0000x reference)
//
#include <hip/hip_runtime.h>
#include <hip/hip_bf16.h>

// Problem constants (B=4, S=2048, H=2048, E=8, K=2)
#define T_TOK 8192
#define H_DIM 2048
#define NE 8

typedef float f32x4 __attribute__((ext_vector_type(4)));
typedef short s16x8 __attribute__((ext_vector_type(8)));

typedef __attribute__((address_space(3))) unsigned int lds_uint;
typedef __attribute__((address_space(1))) const unsigned int glob_uint;

static __device__ __forceinline__ void async_ld16(const void* g, void* l) {
    // 64 lanes x 16B: per-lane global address -> LDS (wave-uniform base + lane*16)
    __builtin_amdgcn_global_load_lds((glob_uint*)g, (lds_uint*)l, 16, 0, 0);
}

static __device__ __forceinline__ unsigned short f32_to_bf16(float f) {
    unsigned int u = __builtin_bit_cast(unsigned int, f);
    return (unsigned short)((u + 0x7FFFu + ((u >> 16) & 1u)) >> 16);
}

static __device__ __forceinline__ float bf2f(unsigned short s) {
    unsigned int u = ((unsigned int)s) << 16;
    return __builtin_bit_cast(float, u);
}

// ---------------------------------------------------------------------------
// Kernel 1 (fused): blocks 0..511 = router (16 tokens each, fused fp32->bf16
// X conversion, fp32 logits, softmax-free top-2, per-block aggregated list
// append with k-slot packed into bits 16+). Blocks 512..2559 = W fp32->bf16
// streaming conversion. Gate is read straight from L2 (64 KiB, hot) so the
// conversion blocks aren't LDS-throttled.
// ---------------------------------------------------------------------------
__global__ __launch_bounds__(256) void prep_router(
        const float* __restrict__ x, const float* __restrict__ gate,
        const float* __restrict__ w,
        unsigned short* __restrict__ xb, unsigned short* __restrict__ wb,
        float* __restrict__ logits, int* __restrict__ cnt,
        int* __restrict__ list, float* __restrict__ wl) {
    __shared__ int aExp[32];
    __shared__ float aW[32];

    if (blockIdx.x >= 512) {
        // ---- W conversion: 2048 blocks x 256 threads x 16 iters ----
        const long g = (long)(blockIdx.x - 512) * 256 + threadIdx.x;
        const float4* w4 = (const float4*)w;
        ushort4* wb4 = (ushort4*)wb;
#pragma unroll
        for (int it = 0; it < 16; ++it) {
            long i = g + (long)it * 524288;
            float4 v = w4[i];
            wb4[i] = make_ushort4(f32_to_bf16(v.x), f32_to_bf16(v.y),
                                  f32_to_bf16(v.z), f32_to_bf16(v.w));
        }
        return;
    }

    // ---- router: 512 blocks x 16 tokens ----
    const int wave = threadIdx.x >> 6, lane = threadIdx.x & 63;
    const float4* g4 = (const float4*)gate;

    for (int it = 0; it < 4; ++it) {
        const int tok = wave * 4 + it;               // 0..15 within block
        const int t = blockIdx.x * 16 + tok;
        const float4* xr = (const float4*)(x + (long)t * H_DIM);
        ushort4* xw = (ushort4*)(xb + (long)t * H_DIM);
        float acc[NE];
#pragma unroll
        for (int e = 0; e < NE; ++e) acc[e] = 0.f;
#pragma unroll
        for (int i = 0; i < 8; ++i) {
            float4 xv = xr[i * 64 + lane];
            xw[i * 64 + lane] = make_ushort4(f32_to_bf16(xv.x), f32_to_bf16(xv.y),
                                             f32_to_bf16(xv.z), f32_to_bf16(xv.w));
#pragma unroll
            for (int e = 0; e < NE; ++e) {
                float4 gv = g4[e * 512 + i * 64 + lane];
                acc[e] += xv.x * gv.x + xv.y * gv.y + xv.z * gv.z + xv.w * gv.w;
            }
        }
#pragma unroll
        for (int e = 0; e < NE; ++e)
#pragma unroll
            for (int off = 32; off > 0; off >>= 1)
                acc[e] += __shfl_xor(acc[e], off, 64);

        if (lane == 0) {
            float l0 = -1e30f; int i0 = 0;
#pragma unroll
            for (int e = 0; e < NE; ++e)
                if (acc[e] > l0) { l0 = acc[e]; i0 = e; }
            float l1 = -1e30f; int i1 = 0;
#pragma unroll
            for (int e = 0; e < NE; ++e)
                if (e != i0 && acc[e] > l1) { l1 = acc[e]; i1 = e; }
            float e1v = __expf(l1 - l0);
            float inv = 1.f / (1.f + e1v);
#pragma unroll
            for (int e = 0; e < NE; ++e) logits[(long)t * NE + e] = acc[e];
            aExp[tok * 2] = i0;     aW[tok * 2] = inv;
            aExp[tok * 2 + 1] = i1; aW[tok * 2 + 1] = e1v * inv;
        }
    }
    __syncthreads();

    if (threadIdx.x < NE) {
        const int e = threadIdx.x;
        int c = 0;
#pragma unroll
        for (int k = 0; k < 32; ++k) c += (aExp[k] == e);
        if (c) {
            int pos = atomicAdd(&cnt[e], c);
            for (int k = 0; k < 32; ++k)
                if (aExp[k] == e) {
                    // pack token id (bits 0..15) and k-slot (bit 16)
                    list[e * T_TOK + pos] = (blockIdx.x * 16 + (k >> 1)) | ((k & 1) << 16);
                    wl[e * T_TOK + pos] = aW[k];
                    ++pos;
                }
        }
    }
}

// ---------------------------------------------------------------------------
// Kernel 2: grouped expert GEMM, async staging, XCD-aware swizzle (all 64
// row-tile blocks of one (e,ct) group land on one XCD so the W slice stays
// L2-resident). 128x128 tile, BK=64, 4 waves of 4x4 16x16x32 bf16 MFMA.
// XOR-swizzled LDS (phys chunk = (r<<3)|(c^(r&7))): conflict-free b128 reads,
// and global_load_lds fetches the permuted logical column per lane.
// DENSE=1: store weighted partials bf16 into y[(tok*2+k)*H] (no atomics, no
// out-zeroing). DENSE=0: atomicAdd fp32 into pre-zeroed out (ws fallback).
// ---------------------------------------------------------------------------
template<int DENSE>
__global__ __launch_bounds__(256, 4) void moe_gemm(
        const unsigned short* __restrict__ xb, const unsigned short* __restrict__ wb,
        const int* __restrict__ cnt, const int* __restrict__ list,
        const float* __restrict__ wl, unsigned short* __restrict__ yb,
        float* __restrict__ out) {
    __shared__ uint4 As[1024];  // 128 rows x 64 bf16 = 16 KiB
    __shared__ uint4 Bs[1024];
    __shared__ int tIdx[128];
    __shared__ float tw[128];

    // XCD swizzle: xcd = bx&7 (round-robin dispatch heuristic)
    const int bx  = blockIdx.x;
    const int xcd = bx & 7;
    const int idx = bx >> 3;          // 0..1023
    const int grp = xcd * 16 + (idx & 15);  // 0..127 = e*16+ct
    const int rt  = idx >> 4;         // 0..63 row tiles
    const int e   = grp >> 4;
    const int ct  = grp & 15;

    const int n = cnt[e];
    const int row0 = rt << 7;
    if (row0 >= n) return;
    const int rv = min(128, n - row0);

    const int tid = threadIdx.x;
    if (tid < 128) {
        if (tid < rv) {
            tIdx[tid] = list[e * T_TOK + row0 + tid];
            tw[tid]   = wl[e * T_TOK + row0 + tid];
        } else { tIdx[tid] = 0; tw[tid] = 0.f; }
    }
    __syncthreads();

    const int wave = tid >> 6, lane = tid & 63;
    const int wm = (wave >> 1) << 6;   // 0 / 64
    const int wn = (wave & 1) << 6;    // 0 / 64
    const int quad = lane >> 4, l16 = lane & 15;

    f32x4 acc[4][4];
#pragma unroll
    for (int i = 0; i < 4; ++i)
#pragma unroll
        for (int j = 0; j < 4; ++j) acc[i][j] = (f32x4){0.f, 0.f, 0.f, 0.f};

    // Per-lane global sources for async staging: phys chunk p = i*256+wave*64+lane
    const unsigned short* aSrc[4];
    const unsigned short* bSrc[4];
    const long wbase = (long)e * H_DIM * H_DIM + (long)(ct * 128) * H_DIM;
#pragma unroll
    for (int i = 0; i < 4; ++i) {
        const int p = i * 256 + wave * 64 + lane;
        const int r = p >> 3;
        const int c = (p & 7) ^ (r & 7);   // logical k-chunk for this phys slot
        aSrc[i] = xb + (long)(tIdx[r] & 0xFFFF) * H_DIM + c * 8;
        bSrc[i] = wb + wbase + (long)r * H_DIM + c * 8;
    }

    for (int kt = 0; kt < H_DIM / 64; ++kt) {
        const int k0 = kt * 64;
#pragma unroll
        for (int i = 0; i < 4; ++i) {
            async_ld16(aSrc[i] + k0, &As[i * 256 + wave * 64]);
            async_ld16(bSrc[i] + k0, &Bs[i * 256 + wave * 64]);
        }
        __syncthreads();
#pragma unroll
        for (int ks = 0; ks < 2; ++ks) {
            s16x8 af[4], bfr[4];
            const int kc = ks * 4 + quad;
#pragma unroll
            for (int i = 0; i < 4; ++i) {
                int r = wm + i * 16 + l16;
                af[i] = ((const s16x8*)As)[(r << 3) | (kc ^ (r & 7))];
            }
#pragma unroll
            for (int j = 0; j < 4; ++j) {
                int d = wn + j * 16 + l16;
                bfr[j] = ((const s16x8*)Bs)[(d << 3) | (kc ^ (d & 7))];
            }
#pragma unroll
            for (int i = 0; i < 4; ++i)
#pragma unroll
                for (int j = 0; j < 4; ++j)
                    acc[i][j] = __builtin_amdgcn_mfma_f32_16x16x32_bf16(
                        af[i], bfr[j], acc[i][j], 0, 0, 0);
        }
        __syncthreads();
    }

    // Epilogue: C/D layout col = lane&15, row = quad*4 + reg.
    const int colbase = ct * 128 + wn;
#pragma unroll
    for (int i = 0; i < 4; ++i) {
        const int rbase = wm + i * 16 + quad * 4;
#pragma unroll
        for (int jr = 0; jr < 4; ++jr) {
            const int r = rbase + jr;
            if (r < rv) {
                const int entry = tIdx[r];
                const float wgt = tw[r];
                if (DENSE) {
                    const long yrow = ((long)(entry & 0xFFFF) << 1) + (entry >> 16);
                    unsigned short* yr = yb + yrow * H_DIM + colbase;
#pragma unroll
                    for (int j = 0; j < 4; ++j)
                        yr[j * 16 + l16] = f32_to_bf16(acc[i][j][jr] * wgt);
                } else {
                    const long orow = (long)(entry & 0xFFFF) * H_DIM + colbase;
#pragma unroll
                    for (int j = 0; j < 4; ++j)
                        atomicAdd(&out[orow + j * 16 + l16], acc[i][j][jr] * wgt);
                }
            }
        }
    }
}

// ---------------------------------------------------------------------------
// Kernel 3: combine. out[t] = y[2t] + y[2t+1] (weights already applied).
// 4096 blocks x 256 threads x 4 float4 each.
// ---------------------------------------------------------------------------
__global__ __launch_bounds__(256) void combine_kernel(
        const unsigned short* __restrict__ yb, float* __restrict__ out) {
    const int g = blockIdx.x * 256 + threadIdx.x;   // 0..1048575
    float4* out4 = (float4*)out;
    const ushort4* y4 = (const ushort4*)yb;
#pragma unroll
    for (int it = 0; it < 4; ++it) {
        const int i = g + it * 1048576;   // float4 index over T*H/4
        const int t = i >> 9, c = i & 511;
        ushort4 a = y4[(long)(t * 2) * 512 + c];
        ushort4 b = y4[(long)(t * 2 + 1) * 512 + c];
        float4 r;
        r.x = bf2f(a.x) + bf2f(b.x);
        r.y = bf2f(a.y) + bf2f(b.y);
        r.z = bf2f(a.z) + bf2f(b.z);
        r.w = bf2f(a.w) + bf2f(b.w);
        out4[i] = r;
    }
}

// ---------------------------------------------------------------------------
extern "C" void kernel_launch(void* const* d_in, const int* in_sizes, int n_in,
                              void* d_out, int out_size, void* d_ws, size_t ws_size,
                              hipStream_t stream) {
    (void)in_sizes; (void)n_in; (void)out_size;
    const float* x    = (const float*)d_in[0];   // [T, H] fp32
    const float* gate = (const float*)d_in[1];   // [E, H] fp32
    const float* w    = (const float*)d_in[2];   // [E, H, H] fp32

    float* out    = (float*)d_out;                       // [T, H]
    float* logits = out + (size_t)T_TOK * H_DIM;         // [T, E]

    char* ws = (char*)d_ws;
    unsigned short* xb = (unsigned short*)(ws);                 // 33,554,432 B
    unsigned short* wb = (unsigned short*)(ws + 33554432);      // 67,108,864 B

    const size_t NEED_DENSE = 168297472;  // xb+wb+yb+cnt+list+wl
    const bool dense = ws_size >= NEED_DENSE;

    unsigned short* yb;
    int* cnt; int* list; float* wl;
    if (dense) {
        yb   = (unsigned short*)(ws + 100663296);   // 67,108,864 B (bf16 y)
        cnt  = (int*)(ws + 167772160);
        list = (int*)(ws + 167773184);              // 262,144 B
        wl   = (float*)(ws + 168035328);            // 262,144 B
    } else {
        yb   = nullptr;
        cnt  = (int*)(ws + 100663296);
        list = (int*)(ws + 100664320);
        wl   = (float*)(ws + 100926464);
    }

    hipMemsetAsync(cnt, 0, NE * sizeof(int), stream);
    if (!dense)
        hipMemsetAsync(out, 0, (size_t)T_TOK * H_DIM * sizeof(float), stream);

    prep_router<<<2560, 256, 0, stream>>>(x, gate, w, xb, wb, logits, cnt, list, wl);
    if (dense) {
        moe_gemm<1><<<8192, 256, 0, stream>>>(xb, wb, cnt, list, wl, yb, out);
        combine_kernel<<<4096, 256, 0, stream>>>(yb, out);
    } else {
        moe_gemm<0><<<8192, 256, 0, stream>>>(xb, wb, cnt, list, wl, yb, out);
    }
}